// Round 2
// baseline (409.072 us; speedup 1.0000x reference)
//
#include <hip/hip_runtime.h>
#include <hip/hip_bf16.h>

typedef unsigned short u16;
typedef __attribute__((ext_vector_type(4))) float f32x4;
typedef __attribute__((ext_vector_type(4))) unsigned int u32x4;
typedef __attribute__((ext_vector_type(4))) unsigned short u16x4;
typedef __attribute__((ext_vector_type(8))) __bf16 bf16x8;

__device__ inline u16 f2u(float f) {
    __hip_bfloat16 b = __float2bfloat16(f);
    return *reinterpret_cast<u16*>(&b);
}
__device__ inline f32x4 mfma16(bf16x8 a, bf16x8 b, f32x4 c) {
    return __builtin_amdgcn_mfma_f32_16x16x32_bf16(a, b, c, 0, 0, 0);
}

// ---------------------------------------------------------------------------
// Generic MFMA GEMM on bf16 ws buffers: C[M,N] = op(A @ B + bias)
//  A: [M,K] row-major (TRANS_A=false) or source [K,M] ld=M (TRANS_A=true)
//  B source: [N,K] ld=K (TRANS_B=false) or [K,N] ld=N (TRANS_B=true)
//  OUT_MODE 0: Out[m*N+n]
//  OUT_MODE 1: head layout: b=m>>logL, l=m&(L-1), h=n>>7, d=n&127
//  OUT_MODE 2: batched z=bh: Out[((z>>3)*M+m)*1024 + (z&7)*128 + n]  (N==128)
//  OUT_F32: write float, else bf16. bias is fp32.
// M,N multiples of 64; K multiple of 64. Block 256 threads = 4 waves (2x2),
// each wave 32x32 via 2x2 mfma_f32_16x16x32_bf16 tiles, BK=64.
// ---------------------------------------------------------------------------
template<bool TRANS_A, bool TRANS_B, int OUT_MODE, bool RELU, bool BIAS, bool OUT_F32>
__global__ __launch_bounds__(256)
void gemm_kernel(const u16* __restrict__ Aall, const u16* __restrict__ Ball,
                 const float* __restrict__ bias, void* __restrict__ OutV,
                 int M, int N, int K, long strideA, long strideB, int logL)
{
    __shared__ __align__(16) u16 As[64][72];
    __shared__ __align__(16) u16 Bs[64][72];
    const int z = blockIdx.z;
    const u16* A  = Aall + (long)z * strideA;
    const u16* Bm = Ball + (long)z * strideB;
    const int n0 = blockIdx.x * 64, m0 = blockIdx.y * 64;
    const int tid = threadIdx.x;
    const int w = tid >> 6, lane = tid & 63, q = lane >> 4, li = lane & 15;
    const int wm = (w >> 1) * 32, wn = (w & 1) * 32;

    f32x4 acc[2][2];
    #pragma unroll
    for (int i = 0; i < 2; i++)
        #pragma unroll
        for (int j = 0; j < 2; j++) acc[i][j] = (f32x4){0.f, 0.f, 0.f, 0.f};

    for (int kt = 0; kt < K; kt += 64) {
        if (!TRANS_A) {
            const int row = tid >> 2, cc = (tid & 3) * 16;
            const u16* src = A + (long)(m0 + row) * K + kt + cc;
            *(u32x4*)&As[row][cc]     = *(const u32x4*)src;
            *(u32x4*)&As[row][cc + 8] = *(const u32x4*)(src + 8);
        } else {
            #pragma unroll
            for (int h = 0; h < 2; h++) {
                const int kr = (tid >> 3) + h * 32, mj = (tid & 7) * 8;
                union { u32x4 v; u16 e[8]; } t;
                t.v = *(const u32x4*)(A + (long)(kt + kr) * M + m0 + mj);
                #pragma unroll
                for (int j = 0; j < 8; j++) As[mj + j][kr] = t.e[j];
            }
        }
        if (!TRANS_B) {
            const int row = tid >> 2, cc = (tid & 3) * 16;
            const u16* src = Bm + (long)(n0 + row) * K + kt + cc;
            *(u32x4*)&Bs[row][cc]     = *(const u32x4*)src;
            *(u32x4*)&Bs[row][cc + 8] = *(const u32x4*)(src + 8);
        } else {
            #pragma unroll
            for (int h = 0; h < 2; h++) {
                const int kr = (tid >> 3) + h * 32, nj = (tid & 7) * 8;
                union { u32x4 v; u16 e[8]; } t;
                t.v = *(const u32x4*)(Bm + (long)(kt + kr) * N + n0 + nj);
                #pragma unroll
                for (int j = 0; j < 8; j++) Bs[nj + j][kr] = t.e[j];
            }
        }
        __syncthreads();
        #pragma unroll
        for (int s = 0; s < 2; s++) {
            bf16x8 a0 = *(bf16x8*)&As[wm + li][s * 32 + q * 8];
            bf16x8 a1 = *(bf16x8*)&As[wm + 16 + li][s * 32 + q * 8];
            bf16x8 b0 = *(bf16x8*)&Bs[wn + li][s * 32 + q * 8];
            bf16x8 b1 = *(bf16x8*)&Bs[wn + 16 + li][s * 32 + q * 8];
            acc[0][0] = mfma16(a0, b0, acc[0][0]);
            acc[0][1] = mfma16(a0, b1, acc[0][1]);
            acc[1][0] = mfma16(a1, b0, acc[1][0]);
            acc[1][1] = mfma16(a1, b1, acc[1][1]);
        }
        __syncthreads();
    }

    #pragma unroll
    for (int i = 0; i < 2; i++) {
        #pragma unroll
        for (int j = 0; j < 2; j++) {
            const int col = n0 + wn + j * 16 + li;
            float bv = 0.f;
            if (BIAS) bv = bias[col];
            #pragma unroll
            for (int r = 0; r < 4; r++) {
                const int row = m0 + wm + i * 16 + q * 4 + r;
                float v = acc[i][j][r] + bv;
                if (RELU) v = fmaxf(v, 0.f);
                long addr;
                if (OUT_MODE == 0) {
                    addr = (long)row * N + col;
                } else if (OUT_MODE == 1) {
                    const int Lm = (1 << logL) - 1;
                    addr = ((long)((row >> logL) * 8 + (col >> 7)) << (logL + 7))
                         + ((long)(row & Lm) << 7) + (col & 127);
                } else {
                    addr = ((long)((z >> 3) * M + row)) * 1024 + ((z & 7) << 7) + col;
                }
                if (OUT_F32) ((float*)OutV)[addr] = v;
                else         ((u16*)OutV)[addr]   = f2u(v);
            }
        }
    }
}

// ---------------------------------------------------------------------------
// Attention: per (m-tile of 16 rows, bh): S = l1 @ p1^T * inter/sqrt(128),
// softmax over LP=1024, write att bf16. 4 waves split the 1024 columns.
// inter is read as fp32 (exact).
// ---------------------------------------------------------------------------
__global__ __launch_bounds__(256)
void attn_kernel(const u16* __restrict__ l1, const u16* __restrict__ p1,
                 const float* __restrict__ inter, u16* __restrict__ att)
{
    __shared__ __align__(16) u16 As[16][136];
    __shared__ float wmax[4][16];
    __shared__ float wsum[4][16];
    const int bh = blockIdx.y;
    const int b  = bh >> 3;
    const int m0 = blockIdx.x * 16;
    const int tid = threadIdx.x;
    const int w = tid >> 6, lane = tid & 63, q = lane >> 4, li = lane & 15;

    {
        const int row = tid >> 4, col = (tid & 15) * 8;
        *(u32x4*)&As[row][col] =
            *(const u32x4*)(l1 + ((long)bh * 256 + m0 + row) * 128 + col);
    }
    __syncthreads();

    bf16x8 af[4];
    #pragma unroll
    for (int s = 0; s < 4; s++) af[s] = *(bf16x8*)&As[li][s * 32 + q * 8];

    float sv[16][4];
    const float rscale = 0.08838834764831845f; // 1/sqrt(128)
    for (int t = 0; t < 16; t++) {
        const int n0 = w * 256 + t * 16;
        const u16* bp = p1 + ((long)bh * 1024 + n0 + li) * 128 + q * 8;
        f32x4 acc = (f32x4){0.f, 0.f, 0.f, 0.f};
        #pragma unroll
        for (int s = 0; s < 4; s++) {
            bf16x8 bfg = *(const bf16x8*)(bp + s * 32);
            acc = mfma16(af[s], bfg, acc);
        }
        const int pcol = n0 + li;
        #pragma unroll
        for (int r = 0; r < 4; r++) {
            const int l = m0 + q * 4 + r;
            float iv = inter[((long)b * 256 + l) * 1024 + pcol];
            sv[t][r] = acc[r] * rscale * iv;
        }
    }

    float rmax[4];
    #pragma unroll
    for (int r = 0; r < 4; r++) {
        float m = sv[0][r];
        #pragma unroll
        for (int t = 1; t < 16; t++) m = fmaxf(m, sv[t][r]);
        for (int d = 1; d < 16; d <<= 1) m = fmaxf(m, __shfl_xor(m, d, 64));
        rmax[r] = m;
    }
    if (li == 0) {
        #pragma unroll
        for (int r = 0; r < 4; r++) wmax[w][q * 4 + r] = rmax[r];
    }
    __syncthreads();
    float gmax[4];
    #pragma unroll
    for (int r = 0; r < 4; r++) {
        gmax[r] = fmaxf(fmaxf(wmax[0][q * 4 + r], wmax[1][q * 4 + r]),
                        fmaxf(wmax[2][q * 4 + r], wmax[3][q * 4 + r]));
    }
    #pragma unroll
    for (int r = 0; r < 4; r++) {
        float s = 0.f;
        #pragma unroll
        for (int t = 0; t < 16; t++) {
            float e = __expf(sv[t][r] - gmax[r]);
            sv[t][r] = e;
            s += e;
        }
        for (int d = 1; d < 16; d <<= 1) s += __shfl_xor(s, d, 64);
        if (li == 0) wsum[w][q * 4 + r] = s;
    }
    __syncthreads();
    float inv[4];
    #pragma unroll
    for (int r = 0; r < 4; r++) {
        float s = wsum[0][q * 4 + r] + wsum[1][q * 4 + r]
                + wsum[2][q * 4 + r] + wsum[3][q * 4 + r];
        inv[r] = 1.f / s;
    }
    for (int t = 0; t < 16; t++) {
        #pragma unroll
        for (int r = 0; r < 4; r++) {
            const int l = m0 + q * 4 + r;
            const int pcol = w * 256 + t * 16 + li;
            att[((long)bh * 256 + l) * 1024 + pcol] = f2u(sv[t][r] * inv[r]);
        }
    }
}

// ---------------------------------------------------------------------------
// Fused 8-way transpose + fp32->bf16 convert for weights: dst[C,R] = bf16(src^T)
// ---------------------------------------------------------------------------
struct TPF { const float* src; u16* dst; int R; int C; };
struct TPF8 { TPF t[8]; };

__global__ __launch_bounds__(256)
void cvtw_kernel(TPF8 args)
{
    TPF tp = args.t[blockIdx.z];
    const int c0 = blockIdx.x * 32, r0 = blockIdx.y * 32;
    if (c0 >= tp.C || r0 >= tp.R) return;
    __shared__ u16 tile[32][33];
    const int tx = threadIdx.x & 31, ty = threadIdx.x >> 5;
    #pragma unroll
    for (int i = 0; i < 4; i++)
        tile[ty + i * 8][tx] = f2u(tp.src[(long)(r0 + ty + i * 8) * tp.C + c0 + tx]);
    __syncthreads();
    #pragma unroll
    for (int i = 0; i < 4; i++)
        tp.dst[(long)(c0 + ty + i * 8) * tp.R + r0 + tx] = tile[tx][ty + i * 8];
}

// ---------------------------------------------------------------------------
// fp32 -> bf16 convert for ligand (z=0) and prot (z=1)
// ---------------------------------------------------------------------------
__global__ __launch_bounds__(256)
void cvt2_kernel(const float* __restrict__ a, u16* __restrict__ da, int na,
                 const float* __restrict__ b, u16* __restrict__ db, int nb)
{
    const int zz = blockIdx.y;
    const float* s = zz ? b : a;
    u16* d = zz ? db : da;
    const int n = zz ? nb : na;
    const int i = (blockIdx.x * 256 + threadIdx.x) * 4;
    if (i >= n) return;
    const float4 v = *(const float4*)(s + i);
    u16x4 o;
    o.x = f2u(v.x); o.y = f2u(v.y); o.z = f2u(v.z); o.w = f2u(v.w);
    *(u16x4*)(d + i) = o;
}

// ---------------------------------------------------------------------------
// Concat (bf16): dst[r][0:128]=a[r], dst[r][128:256]=orig[r], two problems
// ---------------------------------------------------------------------------
__global__ __launch_bounds__(256)
void concat2_kernel(const u16* __restrict__ a0, const u16* __restrict__ o0,
                    u16* __restrict__ d0, int rows0,
                    const u16* __restrict__ a1, const u16* __restrict__ o1,
                    u16* __restrict__ d1, int rows1)
{
    const int zz = blockIdx.y;
    const u16* a = zz ? a1 : a0;
    const u16* o = zz ? o1 : o0;
    u16* dst = zz ? d1 : d0;
    const int rows = zz ? rows1 : rows0;
    const int i = blockIdx.x * 256 + threadIdx.x;
    if (i >= rows * 32) return;
    const int r = i >> 5, c = i & 31;
    const u16* src = (c < 16) ? (a + (long)r * 128 + (long)c * 8)
                              : (o + (long)r * 128 + (long)(c - 16) * 8);
    *(u32x4*)(dst + (long)r * 256 + (long)c * 8) = *(const u32x4*)src;
}

// ---------------------------------------------------------------------------
extern "C" void kernel_launch(void* const* d_in, const int* in_sizes, int n_in,
                              void* d_out, int out_size, void* d_ws, size_t ws_size,
                              hipStream_t stream)
{
    (void)in_sizes; (void)n_in; (void)out_size; (void)ws_size;
    // All inputs are fp32 (reference dtype). Output is fp32.
    const float* ligand = (const float*)d_in[0];
    const float* prot   = (const float*)d_in[1];
    const float* inter  = (const float*)d_in[2];
    const float* Wl1 = (const float*)d_in[3];  const float* bl1 = (const float*)d_in[4];
    const float* Wl2 = (const float*)d_in[5];  const float* bl2 = (const float*)d_in[6];
    const float* Wp1 = (const float*)d_in[7];  const float* bp1 = (const float*)d_in[8];
    const float* Wp2 = (const float*)d_in[9];  const float* bp2 = (const float*)d_in[10];
    const float* W11 = (const float*)d_in[11]; const float* b11 = (const float*)d_in[12];
    const float* W12 = (const float*)d_in[13]; const float* b12 = (const float*)d_in[14];
    const float* W21 = (const float*)d_in[15]; const float* b21 = (const float*)d_in[16];
    const float* W22 = (const float*)d_in[17]; const float* b22 = (const float*)d_in[18];

    float* out0 = (float*)d_out;                    // [16,256,128]
    float* out1 = out0 + (size_t)16 * 256 * 128;    // [16,1024,128]

    u16* ws = (u16*)d_ws;
    size_t off = 0;
    auto alloc = [&](size_t n) { u16* p = ws + off; off += n; return p; };
    u16* ligb  = alloc(524288);    // bf16 ligand [4096,128]
    u16* protb = alloc(2097152);   // bf16 prot  [16384,128]
    u16* l1v   = alloc(4194304);   // [16,8,256,128]
    u16* l2v   = alloc(4194304);
    u16* p1v   = alloc(16777216);  // [16,8,1024,128]
    u16* p2v   = alloc(16777216);
    u16* attv  = alloc(33554432);  // [16,8,256,1024]
    u16* lig3  = alloc(4194304);   // [16,256,1024]
    u16* prot3 = alloc(16777216);  // [16,1024,1024]
    u16* tlig  = alloc(524288);    // [4096,128]
    u16* tprot = alloc(2097152);   // [16384,128]
    u16* clig  = alloc(1048576);   // [4096,256]
    u16* cprot = alloc(4194304);   // [16384,256]
    u16* Wl1t  = alloc(131072);    // [1024,128]
    u16* Wl2t  = alloc(131072);
    u16* Wp1t  = alloc(131072);
    u16* Wp2t  = alloc(131072);
    u16* W11t  = alloc(131072);    // [128,1024]
    u16* W21t  = alloc(131072);
    u16* W12t  = alloc(32768);     // [128,256]
    u16* W22t  = alloc(32768);

    // input conversion
    cvt2_kernel<<<dim3(2048, 2), 256, 0, stream>>>(
        ligand, ligb, 524288, prot, protb, 2097152);

    TPF8 tp;
    tp.t[0] = {Wl1, Wl1t, 128, 1024};
    tp.t[1] = {Wl2, Wl2t, 128, 1024};
    tp.t[2] = {Wp1, Wp1t, 128, 1024};
    tp.t[3] = {Wp2, Wp2t, 128, 1024};
    tp.t[4] = {W11, W11t, 1024, 128};
    tp.t[5] = {W21, W21t, 1024, 128};
    tp.t[6] = {W12, W12t, 256, 128};
    tp.t[7] = {W22, W22t, 256, 128};
    cvtw_kernel<<<dim3(32, 32, 8), 256, 0, stream>>>(tp);

    // projections -> head layout, relu+bias
    gemm_kernel<false,false,1,true,true,false><<<dim3(16,64,1),256,0,stream>>>(
        ligb, Wl1t, bl1, l1v, 4096, 1024, 128, 0, 0, 8);
    gemm_kernel<false,false,1,true,true,false><<<dim3(16,64,1),256,0,stream>>>(
        ligb, Wl2t, bl2, l2v, 4096, 1024, 128, 0, 0, 8);
    gemm_kernel<false,false,1,true,true,false><<<dim3(16,256,1),256,0,stream>>>(
        protb, Wp1t, bp1, p1v, 16384, 1024, 128, 0, 0, 10);
    gemm_kernel<false,false,1,true,true,false><<<dim3(16,256,1),256,0,stream>>>(
        protb, Wp2t, bp2, p2v, 16384, 1024, 128, 0, 0, 10);

    // attention scores + softmax
    attn_kernel<<<dim3(16,128),256,0,stream>>>(l1v, p1v, inter, attv);

    // lig branch: att @ p2 -> [B,LL,H*D]
    gemm_kernel<false,true,2,false,false,false><<<dim3(2,4,128),256,0,stream>>>(
        attv, p2v, nullptr, lig3, 256, 128, 1024, 262144, 131072, 0);
    // prot branch: att^T @ l2 -> [B,LP,H*D]
    gemm_kernel<true,true,2,false,false,false><<<dim3(2,16,128),256,0,stream>>>(
        attv, l2v, nullptr, prot3, 1024, 128, 256, 262144, 32768, 0);

    // x @ W11 + b11 ; x @ W21 + b21
    gemm_kernel<false,false,0,false,true,false><<<dim3(2,64,1),256,0,stream>>>(
        lig3, W11t, b11, tlig, 4096, 128, 1024, 0, 0, 0);
    gemm_kernel<false,false,0,false,true,false><<<dim3(2,256,1),256,0,stream>>>(
        prot3, W21t, b21, tprot, 16384, 128, 1024, 0, 0, 0);

    // concat with residual inputs (bf16)
    concat2_kernel<<<dim3(2048,2),256,0,stream>>>(
        tlig, ligb, clig, 4096, tprot, protb, cprot, 16384);

    // final relu(x @ W12/W22 + b) -> fp32 outputs
    gemm_kernel<false,false,0,true,true,true><<<dim3(2,64,1),256,0,stream>>>(
        clig, W12t, b12, out0, 4096, 128, 256, 0, 0, 0);
    gemm_kernel<false,false,0,true,true,true><<<dim3(2,256,1),256,0,stream>>>(
        cprot, W22t, b22, out1, 16384, 128, 256, 0, 0, 0);
}